// Round 2
// baseline (730.691 us; speedup 1.0000x reference)
//
#include <hip/hip_runtime.h>

// LIF neuron scan, fused single kernel.
// x: [T=500, B=1024, N=256] f32, w: [256] f32
// out: v_seq [T,B] then z_seq [T,B], f32.
//
// Structure: one wave per batch column (1024 waves total = 256 blocks x 4
// waves = exactly 1 block per CU). The wave computes x[t,c,:] . w via a
// 64-lane float4 load (1 KB coalesced) + butterfly reduction, then advances
// the v/z recurrence in-register -- the dot producer IS the recurrence owner,
// so no LDS, no barriers, no intermediate global round-trip.
// 4-deep register prefetch keeps ~16 KB/CU of global loads in flight to
// saturate HBM (~10 B/cyc/CU needed at ~900 cyc miss latency).

#define T_STEPS 500
#define BATCH   1024
#define NDIM    256
#define ALPHA_F 0.995f
#define TSTRIDE ((size_t)BATCH * NDIM)   // floats per timestep

__global__ __launch_bounds__(256) void lif_fused_kernel(
    const float* __restrict__ x, const float* __restrict__ w,
    float* __restrict__ vout, float* __restrict__ zout)
{
    const int wave = threadIdx.x >> 6;
    const int lane = threadIdx.x & 63;
    const int c    = blockIdx.x * 4 + wave;   // batch column, 0..1023

    const float4 wv = *(const float4*)(w + lane * 4);
    const float* xbase = x + (size_t)c * NDIM + lane * 4;

    float v = 0.0f, z = 0.0f;

    float4 cur[4], nxt[4];
#pragma unroll
    for (int j = 0; j < 4; ++j)
        cur[j] = *(const float4*)(xbase + (size_t)j * TSTRIDE);

    for (int t0 = 0; t0 < T_STEPS; t0 += 4) {
        // prefetch next group (clamped at tail; extra reloads are unused)
        const int tp = (t0 + 4 < T_STEPS) ? (t0 + 4) : t0;
#pragma unroll
        for (int j = 0; j < 4; ++j)
            nxt[j] = *(const float4*)(xbase + (size_t)(tp + j) * TSTRIDE);

#pragma unroll
        for (int j = 0; j < 4; ++j) {
            float p = cur[j].x * wv.x + cur[j].y * wv.y
                    + cur[j].z * wv.z + cur[j].w * wv.w;
            // 64-lane butterfly: all lanes end with the full dot product
            p += __shfl_xor(p, 32, 64);
            p += __shfl_xor(p, 16, 64);
            p += __shfl_xor(p, 8, 64);
            p += __shfl_xor(p, 4, 64);
            p += __shfl_xor(p, 2, 64);
            p += __shfl_xor(p, 1, 64);

            v = ALPHA_F * v + p - z;              // v_th = 1
            z = (v - 1.0f > 0.0f) ? 1.0f : 0.0f;

            const size_t o = (size_t)(t0 + j) * BATCH + c;
            if (lane == 0) vout[o] = v;
            if (lane == 1) zout[o] = z;
        }
#pragma unroll
        for (int j = 0; j < 4; ++j) cur[j] = nxt[j];
    }
}

extern "C" void kernel_launch(void* const* d_in, const int* in_sizes, int n_in,
                              void* d_out, int out_size, void* d_ws, size_t ws_size,
                              hipStream_t stream)
{
    const float* x = (const float*)d_in[0];   // [T, B, N] f32
    const float* w = (const float*)d_in[1];   // [N] f32
    float* out  = (float*)d_out;
    float* vout = out;                                   // v_seq [T,B]
    float* zout = out + (size_t)T_STEPS * BATCH;         // z_seq [T,B]

    lif_fused_kernel<<<BATCH / 4, 256, 0, stream>>>(x, w, vout, zout);
}

// Round 3
// 676.296 us; speedup vs baseline: 1.0804x; 1.0804x over previous
//
#include <hip/hip_runtime.h>

// LIF neuron scan, fused single kernel, 16-deep register-ring prefetch.
// x: [T=500, B=1024, N=256] f32, w: [256] f32
// out: v_seq [T,B] then z_seq [T,B], f32.
//
// One wave per batch column (1024 waves = 256 blocks x 4 waves = 1 block/CU).
// Wave computes x[t,c,:].w via 64-lane float4 load + butterfly reduce, then
// advances v/z in-register (producer == recurrence owner, no LDS/barriers).
// R2 ran ~170us (latency-bound): 4 waves/CU x 4KB prefetch = 16KB/CU in
// flight -> only ~5-8 B/cyc at loaded HBM latency. Fix: 16-deep ring
// (16KB/wave, 64KB/CU in flight) with per-slot vmcnt waits.

#define T_STEPS 500
#define BATCH   1024
#define NDIM    256
#define ALPHA_F 0.995f
#define TSTRIDE ((size_t)BATCH * NDIM)   // floats per timestep
#define DEPTH   16

__global__ __launch_bounds__(256) void lif_fused_kernel(
    const float* __restrict__ x, const float* __restrict__ w,
    float* __restrict__ vout, float* __restrict__ zout)
{
    const int wave = threadIdx.x >> 6;
    const int lane = threadIdx.x & 63;
    const int c    = blockIdx.x * 4 + wave;   // batch column, 0..1023

    const float4 wv = *(const float4*)(w + lane * 4);
    const float* xbase = x + (size_t)c * NDIM + lane * 4;

    float v = 0.0f, z = 0.0f;

    auto step = [&](const float4 xv, const int t) {
        float p = xv.x * wv.x + xv.y * wv.y + xv.z * wv.z + xv.w * wv.w;
        p += __shfl_xor(p, 32, 64);
        p += __shfl_xor(p, 16, 64);
        p += __shfl_xor(p, 8, 64);
        p += __shfl_xor(p, 4, 64);
        p += __shfl_xor(p, 2, 64);
        p += __shfl_xor(p, 1, 64);
        v = ALPHA_F * v + p - z;              // v_th = 1
        z = (v - 1.0f > 0.0f) ? 1.0f : 0.0f;
        const size_t o = (size_t)t * BATCH + c;
        if (lane == 0) vout[o] = v;
        if (lane == 1) zout[o] = z;
    };

    // prologue: fill the 16-slot ring with t = 0..15
    float4 buf[DEPTH];
#pragma unroll
    for (int j = 0; j < DEPTH; ++j)
        buf[j] = *(const float4*)(xbase + (size_t)j * TSTRIDE);

    // main: t = 0..479; slot j's prefetch (t+16 <= 495) is always in-bounds.
    // Copy-out then immediately re-issue the load so the prefetch sits ahead
    // of the compute; the wait for slot j lands 15 slots later.
    for (int t0 = 0; t0 < T_STEPS - 2 * DEPTH + 12; t0 += DEPTH) {  // 0..464
#pragma unroll
        for (int j = 0; j < DEPTH; ++j) {
            const int t = t0 + j;
            const float4 xv = buf[j];
            buf[j] = *(const float4*)(xbase + (size_t)(t + DEPTH) * TSTRIDE);
            step(xv, t);
        }
    }

    // epilogue: ring holds t=480..495; t=496..499 need direct loads.
    float4 buf2[4];
#pragma unroll
    for (int j = 0; j < 4; ++j)
        buf2[j] = *(const float4*)(xbase + (size_t)(496 + j) * TSTRIDE);
#pragma unroll
    for (int j = 0; j < DEPTH; ++j)
        step(buf[j], 480 + j);
#pragma unroll
    for (int j = 0; j < 4; ++j)
        step(buf2[j], 496 + j);
}

extern "C" void kernel_launch(void* const* d_in, const int* in_sizes, int n_in,
                              void* d_out, int out_size, void* d_ws, size_t ws_size,
                              hipStream_t stream)
{
    const float* x = (const float*)d_in[0];   // [T, B, N] f32
    const float* w = (const float*)d_in[1];   // [N] f32
    float* out  = (float*)d_out;
    float* vout = out;                                   // v_seq [T,B]
    float* zout = out + (size_t)T_STEPS * BATCH;         // z_seq [T,B]

    lif_fused_kernel<<<BATCH / 4, 256, 0, stream>>>(x, w, vout, zout);
}